// Round 1
// baseline (364.506 us; speedup 1.0000x reference)
//
#include <hip/hip_runtime.h>

// LSTMNet: 3-layer LSTM (H=6, input 1), B=8192, T=512, final FC to 1 output.
// Strategy: 8 lanes per batch element; lane j (0..5) owns hidden unit j for
// all three layers; weights live in VGPRs; h broadcast via ds_bpermute.
// fp32 throughout (threshold 4.55e-3 absmax; hw exp2/rcp are ~1 ulp).

#define HID 6
#define SEQT 512

__device__ __forceinline__ float fast_exp2(float x) { return __builtin_amdgcn_exp2f(x); }
__device__ __forceinline__ float fast_rcp(float x)  { return __builtin_amdgcn_rcpf(x); }

// sigmoid(x) = 1/(1+e^-x) = rcp(1 + 2^(-x*log2e))
__device__ __forceinline__ float sigmoidf_(float x) {
    return fast_rcp(1.0f + fast_exp2(-1.4426950408889634f * x));
}
// tanh(x) = 1 - 2/(1+e^(2x)) = 1 - 2*rcp(1 + 2^(x*2*log2e))
__device__ __forceinline__ float tanhf_(float x) {
    return 1.0f - 2.0f * fast_rcp(1.0f + fast_exp2(2.8853900817779268f * x));
}

#define LSTM_CELL(P0, P1, P2, P3, hvar, cvar)              \
    {                                                      \
        float i_ = sigmoidf_(P0);                          \
        float f_ = sigmoidf_(P1);                          \
        float g_ = tanhf_(P2);                             \
        float o_ = sigmoidf_(P3);                          \
        cvar = f_ * cvar + i_ * g_;                        \
        hvar = o_ * tanhf_(cvar);                          \
    }

#define BCAST6(dst, src)                                   \
    {                                                      \
        _Pragma("unroll")                                  \
        for (int k_ = 0; k_ < 6; ++k_)                     \
            dst[k_] = __shfl(src, base + k_, 64);          \
    }

__global__ __launch_bounds__(256, 1) void lstm3_kernel(
    const float* __restrict__ x,
    const float* __restrict__ Wih0, const float* __restrict__ Whh0,
    const float* __restrict__ bih0, const float* __restrict__ bhh0,
    const float* __restrict__ Wih1, const float* __restrict__ Whh1,
    const float* __restrict__ bih1, const float* __restrict__ bhh1,
    const float* __restrict__ Wih2, const float* __restrict__ Whh2,
    const float* __restrict__ bih2, const float* __restrict__ bhh2,
    const float* __restrict__ fcw, const float* __restrict__ fcb,
    float* __restrict__ out)
{
    const int tid  = blockIdx.x * blockDim.x + threadIdx.x;
    const int lane = threadIdx.x & 63;
    const int sub  = lane & 7;        // position within 8-lane group
    const int base = lane & ~7;       // group base lane within wave
    const int b    = tid >> 3;        // batch element for this group
    const int j    = (sub < 6) ? sub : (sub - 6);  // hidden unit (6,7 dup 0,1)

    // ---- Load per-lane weights into registers (one-time; cache-served) ----
    // Gate g (0=i,1=f,2=g,3=o) for unit j is weight row 6*g + j.
    float wi0[4], b0[4], whh0[4][6];
    float wih1[4][6], whh1[4][6], b1[4];
    float wih2[4][6], whh2[4][6], b2[4];
#pragma unroll
    for (int g = 0; g < 4; ++g) {
        const int row = 6 * g + j;
        wi0[g] = Wih0[row];
        b0[g]  = bih0[row] + bhh0[row];
        b1[g]  = bih1[row] + bhh1[row];
        b2[g]  = bih2[row] + bhh2[row];
#pragma unroll
        for (int k = 0; k < 6; ++k) {
            whh0[g][k] = Whh0[row * 6 + k];
            wih1[g][k] = Wih1[row * 6 + k];
            whh1[g][k] = Whh1[row * 6 + k];
            wih2[g][k] = Wih2[row * 6 + k];
            whh2[g][k] = Whh2[row * 6 + k];
        }
    }

    float h0 = 0.f, c0 = 0.f, h1 = 0.f, c1 = 0.f, h2 = 0.f, c2 = 0.f;
    float h0a[6] = {0, 0, 0, 0, 0, 0};
    float h1a[6] = {0, 0, 0, 0, 0, 0};
    float h2a[6] = {0, 0, 0, 0, 0, 0};

    const float* xrow = x + (size_t)b * SEQT;

    for (int t8 = 0; t8 < SEQT; t8 += 8) {
        // prefetch 8 timesteps of x across the group's 8 lanes
        float xv = xrow[t8 + sub];
#pragma unroll
        for (int s = 0; s < 8; ++s) {
            const float xt = __shfl(xv, base + s, 64);

            // ---------------- layer 0 (input = scalar xt) ----------------
            float p0 = fmaf(wi0[0], xt, b0[0]);
            float p1 = fmaf(wi0[1], xt, b0[1]);
            float p2 = fmaf(wi0[2], xt, b0[2]);
            float p3 = fmaf(wi0[3], xt, b0[3]);
#pragma unroll
            for (int k = 0; k < 6; ++k) {
                p0 = fmaf(whh0[0][k], h0a[k], p0);
                p1 = fmaf(whh0[1][k], h0a[k], p1);
                p2 = fmaf(whh0[2][k], h0a[k], p2);
                p3 = fmaf(whh0[3][k], h0a[k], p3);
            }
            LSTM_CELL(p0, p1, p2, p3, h0, c0);
            BCAST6(h0a, h0);

            // ---------------- layer 1 (input = h0a) ----------------
            p0 = b1[0]; p1 = b1[1]; p2 = b1[2]; p3 = b1[3];
#pragma unroll
            for (int k = 0; k < 6; ++k) {
                p0 = fmaf(wih1[0][k], h0a[k], fmaf(whh1[0][k], h1a[k], p0));
                p1 = fmaf(wih1[1][k], h0a[k], fmaf(whh1[1][k], h1a[k], p1));
                p2 = fmaf(wih1[2][k], h0a[k], fmaf(whh1[2][k], h1a[k], p2));
                p3 = fmaf(wih1[3][k], h0a[k], fmaf(whh1[3][k], h1a[k], p3));
            }
            LSTM_CELL(p0, p1, p2, p3, h1, c1);
            BCAST6(h1a, h1);

            // ---------------- layer 2 (input = h1a) ----------------
            p0 = b2[0]; p1 = b2[1]; p2 = b2[2]; p3 = b2[3];
#pragma unroll
            for (int k = 0; k < 6; ++k) {
                p0 = fmaf(wih2[0][k], h1a[k], fmaf(whh2[0][k], h2a[k], p0));
                p1 = fmaf(wih2[1][k], h1a[k], fmaf(whh2[1][k], h2a[k], p1));
                p2 = fmaf(wih2[2][k], h1a[k], fmaf(whh2[2][k], h2a[k], p2));
                p3 = fmaf(wih2[3][k], h1a[k], fmaf(whh2[3][k], h2a[k], p3));
            }
            LSTM_CELL(p0, p1, p2, p3, h2, c2);
            BCAST6(h2a, h2);
        }
    }

    // ---- final FC: out[b] = fc_b + sum_k fcw[k] * h2[k] ----
    if (sub == 0) {
        float o = fcb[0];
#pragma unroll
        for (int k = 0; k < 6; ++k)
            o = fmaf(fcw[k], h2a[k], o);
        out[b] = o;
    }
}

extern "C" void kernel_launch(void* const* d_in, const int* in_sizes, int n_in,
                              void* d_out, int out_size, void* d_ws, size_t ws_size,
                              hipStream_t stream) {
    const float* x    = (const float*)d_in[0];
    const float* Wih0 = (const float*)d_in[1];
    const float* Whh0 = (const float*)d_in[2];
    const float* bih0 = (const float*)d_in[3];
    const float* bhh0 = (const float*)d_in[4];
    const float* Wih1 = (const float*)d_in[5];
    const float* Whh1 = (const float*)d_in[6];
    const float* bih1 = (const float*)d_in[7];
    const float* bhh1 = (const float*)d_in[8];
    const float* Wih2 = (const float*)d_in[9];
    const float* Whh2 = (const float*)d_in[10];
    const float* bih2 = (const float*)d_in[11];
    const float* bhh2 = (const float*)d_in[12];
    const float* fcw  = (const float*)d_in[13];
    const float* fcb  = (const float*)d_in[14];
    float* out = (float*)d_out;

    const int B = out_size;            // 8192
    const int threads = B * 8;         // 8 lanes per batch element
    const int block = 256;
    const int grid = threads / block;  // 2048 threads? no: 65536/256 = 256 blocks
    lstm3_kernel<<<grid, block, 0, stream>>>(
        x, Wih0, Whh0, bih0, bhh0, Wih1, Whh1, bih1, bhh1,
        Wih2, Whh2, bih2, bhh2, fcw, fcb, out);
}

// Round 2
// 360.210 us; speedup vs baseline: 1.0119x; 1.0119x over previous
//
#include <hip/hip_runtime.h>

// LSTMNet: 3-layer LSTM (H=6, in=1), B=8192, T=512, FC to 1.
// R2 layout: 16 lanes per batch element = 2 waves/SIMD occupancy.
//   sub = lane&15; p = sub>>3 (gate-pair half), j = unit 0..5 (subs 6,7,14,15 dup).
//   p0 lane computes gates i,f for unit j; p1 lane computes gates g,o.
//   Weights pre-scaled by -log2e (sigmoid rows) / +2log2e (tanh row) so
//   activation = fma(A, rcp(1+exp2(z)), B) with per-lane constants A,B.
//   Gate exchange via ds_swizzle xor-8 (0x201F); h broadcast via ds_swizzle
//   bcast patterns (lane&0x10)|k. Recurrent dots computed first each step so
//   the scheduler can hide broadcast/trans latency under them.

#define SEQT 512

__device__ __forceinline__ float fexp2(float x) { return __builtin_amdgcn_exp2f(x); }
__device__ __forceinline__ float frcp(float x)  { return __builtin_amdgcn_rcpf(x); }

template <int OFF>
__device__ __forceinline__ float swz(float v) {
    return __int_as_float(__builtin_amdgcn_ds_swizzle(__float_as_int(v), OFF));
}

// z already scaled: sigmoid rows by -log2e, tanh rows by +2*log2e.
// sigmoid: A=1,B=0 -> rcp(1+exp2(z)). tanh: A=-2,B=1 -> 1-2*rcp(1+exp2(z)).
__device__ __forceinline__ float act(float z, float A, float B) {
    float r = frcp(1.0f + fexp2(z));
    return fmaf(A, r, B);
}
__device__ __forceinline__ float tanh_c(float c) {
    return 1.0f - 2.0f * frcp(1.0f + fexp2(2.8853900817779268f * c));
}

// broadcast from lanes (lane&0x10)|k within each 16-lane group (BitMode:
// offset = (or<<5) | and ; and=0x10 keeps the group-of-16 bit within the
// 32-lane swizzle domain, or=k selects the source sub-lane).
#define BCAST6(dst, src)              \
    dst[0] = swz<0x010>(src);         \
    dst[1] = swz<0x030>(src);         \
    dst[2] = swz<0x050>(src);         \
    dst[3] = swz<0x070>(src);         \
    dst[4] = swz<0x090>(src);         \
    dst[5] = swz<0x0B0>(src);

#define XCHG 0x201F  // xor=8: partner lane within 16-group (p0<->p1)

__global__ __launch_bounds__(256, 2) void lstm3_kernel(
    const float* __restrict__ x,
    const float* __restrict__ Wih0, const float* __restrict__ Whh0,
    const float* __restrict__ bih0, const float* __restrict__ bhh0,
    const float* __restrict__ Wih1, const float* __restrict__ Whh1,
    const float* __restrict__ bih1, const float* __restrict__ bhh1,
    const float* __restrict__ Wih2, const float* __restrict__ Whh2,
    const float* __restrict__ bih2, const float* __restrict__ bhh2,
    const float* __restrict__ fcw, const float* __restrict__ fcb,
    float* __restrict__ out)
{
    const int tid  = blockIdx.x * blockDim.x + threadIdx.x;
    const int lane = threadIdx.x & 63;
    const int sub  = lane & 15;
    const int wb16 = lane & ~15;              // 16-group base lane in wave
    const int p    = sub >> 3;                // 0: gates i,f   1: gates g,o
    const int jj   = sub & 7;
    const int j    = (jj < 6) ? jj : jj - 6;  // unit (subs 6,7 duplicate 0,1)
    const int b    = tid >> 4;                // batch element

    const float L2E = 1.4426950408889634f;
    const float s0  = p ? 2.0f * L2E : -L2E;  // row g0 scale (g-gate is tanh)
    const float s1  = -L2E;                   // row g1 scale (f and o: sigmoid)
    const float A0  = p ? -2.0f : 1.0f;
    const float B0  = p ? 1.0f : 0.0f;

    const int g0 = 2 * p, g1 = 2 * p + 1;
    const int r0 = 6 * g0 + j, r1 = 6 * g1 + j;

    // ---- load + pre-scale weights into registers ----
    float wx0 = Wih0[r0] * s0, wx1 = Wih0[r1] * s1;
    float b00 = (bih0[r0] + bhh0[r0]) * s0, b01 = (bih0[r1] + bhh0[r1]) * s1;
    float b10 = (bih1[r0] + bhh1[r0]) * s0, b11 = (bih1[r1] + bhh1[r1]) * s1;
    float b20 = (bih2[r0] + bhh2[r0]) * s0, b21 = (bih2[r1] + bhh2[r1]) * s1;

    float whh0a[6], whh0b[6];
    float wih1a[6], wih1b[6], whh1a[6], whh1b[6];
    float wih2a[6], wih2b[6], whh2a[6], whh2b[6];
#pragma unroll
    for (int k = 0; k < 6; ++k) {
        whh0a[k] = Whh0[r0 * 6 + k] * s0;  whh0b[k] = Whh0[r1 * 6 + k] * s1;
        wih1a[k] = Wih1[r0 * 6 + k] * s0;  wih1b[k] = Wih1[r1 * 6 + k] * s1;
        whh1a[k] = Whh1[r0 * 6 + k] * s0;  whh1b[k] = Whh1[r1 * 6 + k] * s1;
        wih2a[k] = Wih2[r0 * 6 + k] * s0;  wih2b[k] = Wih2[r1 * 6 + k] * s1;
        whh2a[k] = Whh2[r0 * 6 + k] * s0;  whh2b[k] = Whh2[r1 * 6 + k] * s1;
    }

    float h0a[6] = {0, 0, 0, 0, 0, 0};
    float h1a[6] = {0, 0, 0, 0, 0, 0};
    float h2a[6] = {0, 0, 0, 0, 0, 0};
    float c0 = 0.f, c1 = 0.f, c2 = 0.f;

    const float* xrow = x + (size_t)b * SEQT;

    for (int t16 = 0; t16 < SEQT; t16 += 16) {
        float xv = xrow[t16 + sub];  // 16 timesteps staged across the group
        for (int s = 0; s < 16; ++s) {
            // ---- recurrent dots for ALL layers first (independent work) ----
            float z00 = b00, z01 = b01, z10 = b10, z11 = b11, z20 = b20, z21 = b21;
#pragma unroll
            for (int k = 0; k < 6; ++k) {
                z00 = fmaf(whh0a[k], h0a[k], z00);
                z01 = fmaf(whh0b[k], h0a[k], z01);
            }
#pragma unroll
            for (int k = 0; k < 6; ++k) {
                z10 = fmaf(whh1a[k], h1a[k], z10);
                z11 = fmaf(whh1b[k], h1a[k], z11);
            }
#pragma unroll
            for (int k = 0; k < 6; ++k) {
                z20 = fmaf(whh2a[k], h2a[k], z20);
                z21 = fmaf(whh2b[k], h2a[k], z21);
            }

            const float xt = __shfl(xv, wb16 + s, 64);
            z00 = fmaf(wx0, xt, z00);
            z01 = fmaf(wx1, xt, z01);

            // ---------------- layer 0 ----------------
            {
                float a0 = act(z00, A0, B0);        // p0: i     p1: g
                float a1 = act(z01, 1.0f, 0.0f);    // p0: f     p1: o
                float gx = swz<XCHG>(a0);           // on p0: g
                float ox = swz<XCHG>(a1);           // on p0: o
                c0 = fmaf(a1, c0, a0 * gx);         // c = f*c + i*g (valid on p0)
                float h = ox * tanh_c(c0);
                BCAST6(h0a, h);                     // reads p0 lanes 0..5
            }

            // ---------------- layer 1 ----------------
#pragma unroll
            for (int k = 0; k < 6; ++k) {
                z10 = fmaf(wih1a[k], h0a[k], z10);
                z11 = fmaf(wih1b[k], h0a[k], z11);
            }
            {
                float a0 = act(z10, A0, B0);
                float a1 = act(z11, 1.0f, 0.0f);
                float gx = swz<XCHG>(a0);
                float ox = swz<XCHG>(a1);
                c1 = fmaf(a1, c1, a0 * gx);
                float h = ox * tanh_c(c1);
                BCAST6(h1a, h);
            }

            // ---------------- layer 2 ----------------
#pragma unroll
            for (int k = 0; k < 6; ++k) {
                z20 = fmaf(wih2a[k], h1a[k], z20);
                z21 = fmaf(wih2b[k], h1a[k], z21);
            }
            {
                float a0 = act(z20, A0, B0);
                float a1 = act(z21, 1.0f, 0.0f);
                float gx = swz<XCHG>(a0);
                float ox = swz<XCHG>(a1);
                c2 = fmaf(a1, c2, a0 * gx);
                float h = ox * tanh_c(c2);
                BCAST6(h2a, h);
            }
        }
    }

    // ---- final FC ----
    if (sub == 0) {
        float o = fcb[0];
#pragma unroll
        for (int k = 0; k < 6; ++k)
            o = fmaf(fcw[k], h2a[k], o);
        out[b] = o;
    }
}

extern "C" void kernel_launch(void* const* d_in, const int* in_sizes, int n_in,
                              void* d_out, int out_size, void* d_ws, size_t ws_size,
                              hipStream_t stream) {
    const float* x    = (const float*)d_in[0];
    const float* Wih0 = (const float*)d_in[1];
    const float* Whh0 = (const float*)d_in[2];
    const float* bih0 = (const float*)d_in[3];
    const float* bhh0 = (const float*)d_in[4];
    const float* Wih1 = (const float*)d_in[5];
    const float* Whh1 = (const float*)d_in[6];
    const float* bih1 = (const float*)d_in[7];
    const float* bhh1 = (const float*)d_in[8];
    const float* Wih2 = (const float*)d_in[9];
    const float* Whh2 = (const float*)d_in[10];
    const float* bih2 = (const float*)d_in[11];
    const float* bhh2 = (const float*)d_in[12];
    const float* fcw  = (const float*)d_in[13];
    const float* fcb  = (const float*)d_in[14];
    float* out = (float*)d_out;

    const int B = out_size;            // 8192
    const int threads = B * 16;        // 16 lanes per batch element
    const int block = 256;
    const int grid = threads / block;  // 512 blocks -> 2 blocks/CU -> 2 waves/SIMD
    lstm3_kernel<<<grid, block, 0, stream>>>(
        x, Wih0, Whh0, bih0, bhh0, Wih1, Whh1, bih1, bhh1,
        Wih2, Whh2, bih2, bhh2, fcw, fcb, out);
}

// Round 3
// 348.894 us; speedup vs baseline: 1.0447x; 1.0324x over previous
//
#include <hip/hip_runtime.h>

// LSTMNet: 3-layer LSTM (H=6, in=1), B=8192, T=512, FC to 1.
// R3: R2's 16-lane gate-split layout + two fixes driven by rocprof:
//  (a) FETCH_SIZE was 8.2 GB (ideal ~30 MB) with VGPR_Count=52: the compiler
//      sank the ~60 loop-invariant weight loads into the innermost ts loop.
//      Fix: pin every weight in a VGPR via opaque asm after pre-scaling.
//  (b) x distributed via float4 self-load (16 lanes same addr -> broadcast),
//      software-pipelined one t4-iteration ahead; no x shuffles.
// Layout: sub=lane&15; p=sub>>3 selects gate pair (p0: i,f | p1: g,o);
// j=unit 0..5 (subs 6,7 duplicate). Weights pre-scaled by -log2e (sigmoid)
// or +2log2e (tanh) so act = fma(A, rcp(1+exp2(z)), B).

#define SEQT 512

__device__ __forceinline__ float fexp2(float x) { return __builtin_amdgcn_exp2f(x); }
__device__ __forceinline__ float frcp(float x)  { return __builtin_amdgcn_rcpf(x); }

// Force value into a VGPR; opaque to the optimizer (prevents load remat/sink).
#define PIN(v) asm volatile("" : "+v"(v))

template <int OFF>
__device__ __forceinline__ float swz(float v) {
    return __int_as_float(__builtin_amdgcn_ds_swizzle(__float_as_int(v), OFF));
}

__device__ __forceinline__ float act(float z, float A, float B) {
    float r = frcp(1.0f + fexp2(z));
    return fmaf(A, r, B);
}
__device__ __forceinline__ float tanh_c(float c) {
    return 1.0f - 2.0f * frcp(1.0f + fexp2(2.8853900817779268f * c));
}

// broadcast from lane (lane&0x10)|k within 16-lane group (swizzle BitMode)
#define BCAST6(dst, src)              \
    dst[0] = swz<0x010>(src);         \
    dst[1] = swz<0x030>(src);         \
    dst[2] = swz<0x050>(src);         \
    dst[3] = swz<0x070>(src);         \
    dst[4] = swz<0x090>(src);         \
    dst[5] = swz<0x0B0>(src);

#define XCHG 0x201F  // xor=8: partner lane (p0<->p1) within 16-group

__global__ __launch_bounds__(256, 2) void lstm3_kernel(
    const float* __restrict__ x,
    const float* __restrict__ Wih0, const float* __restrict__ Whh0,
    const float* __restrict__ bih0, const float* __restrict__ bhh0,
    const float* __restrict__ Wih1, const float* __restrict__ Whh1,
    const float* __restrict__ bih1, const float* __restrict__ bhh1,
    const float* __restrict__ Wih2, const float* __restrict__ Whh2,
    const float* __restrict__ bih2, const float* __restrict__ bhh2,
    const float* __restrict__ fcw, const float* __restrict__ fcb,
    float* __restrict__ out)
{
    const int tid  = blockIdx.x * blockDim.x + threadIdx.x;
    const int lane = threadIdx.x & 63;
    const int sub  = lane & 15;
    const int p    = sub >> 3;                // 0: gates i,f   1: gates g,o
    const int jj   = sub & 7;
    const int j    = (jj < 6) ? jj : jj - 6;  // unit (subs 6,7 duplicate 0,1)
    const int b    = tid >> 4;                // batch element

    const float L2E = 1.4426950408889634f;
    const float s0  = p ? 2.0f * L2E : -L2E;  // first row of pair (i or g)
    const float s1  = -L2E;                   // second row (f or o): sigmoid
    const float A0  = p ? -2.0f : 1.0f;
    const float B0  = p ? 1.0f : 0.0f;

    const int g0 = 2 * p, g1 = 2 * p + 1;
    const int r0 = 6 * g0 + j, r1 = 6 * g1 + j;

    // ---- load + pre-scale weights, then PIN each into a VGPR ----
    float wx0 = Wih0[r0] * s0, wx1 = Wih0[r1] * s1;
    float b00 = (bih0[r0] + bhh0[r0]) * s0, b01 = (bih0[r1] + bhh0[r1]) * s1;
    float b10 = (bih1[r0] + bhh1[r0]) * s0, b11 = (bih1[r1] + bhh1[r1]) * s1;
    float b20 = (bih2[r0] + bhh2[r0]) * s0, b21 = (bih2[r1] + bhh2[r1]) * s1;
    PIN(wx0); PIN(wx1); PIN(b00); PIN(b01);
    PIN(b10); PIN(b11); PIN(b20); PIN(b21);

    float whh0a[6], whh0b[6];
    float wih1a[6], wih1b[6], whh1a[6], whh1b[6];
    float wih2a[6], wih2b[6], whh2a[6], whh2b[6];
#pragma unroll
    for (int k = 0; k < 6; ++k) {
        whh0a[k] = Whh0[r0 * 6 + k] * s0;  whh0b[k] = Whh0[r1 * 6 + k] * s1;
        wih1a[k] = Wih1[r0 * 6 + k] * s0;  wih1b[k] = Wih1[r1 * 6 + k] * s1;
        whh1a[k] = Whh1[r0 * 6 + k] * s0;  whh1b[k] = Whh1[r1 * 6 + k] * s1;
        wih2a[k] = Wih2[r0 * 6 + k] * s0;  wih2b[k] = Wih2[r1 * 6 + k] * s1;
        whh2a[k] = Whh2[r0 * 6 + k] * s0;  whh2b[k] = Whh2[r1 * 6 + k] * s1;
        PIN(whh0a[k]); PIN(whh0b[k]);
        PIN(wih1a[k]); PIN(wih1b[k]);
        PIN(whh1a[k]); PIN(whh1b[k]);
        PIN(wih2a[k]); PIN(wih2b[k]);
        PIN(whh2a[k]); PIN(whh2b[k]);
    }

    float h0a[6] = {0, 0, 0, 0, 0, 0};
    float h1a[6] = {0, 0, 0, 0, 0, 0};
    float h2a[6] = {0, 0, 0, 0, 0, 0};
    float c0 = 0.f, c1 = 0.f, c2 = 0.f;

    const float4* xq = (const float4*)(x + (size_t)b * SEQT);

    float4 q = xq[0];  // all 16 lanes of the group load the same 16B

    for (int t4 = 0; t4 < SEQT / 4; ++t4) {
        float4 qn;
        if (t4 + 1 < SEQT / 4) qn = xq[t4 + 1];  // prefetch next quad

        float xts[4] = {q.x, q.y, q.z, q.w};
#pragma unroll
        for (int s = 0; s < 4; ++s) {
            const float xt = xts[s];

            // ---- recurrent dots for ALL layers first (independent ILP) ----
            float z00 = fmaf(wx0, xt, b00), z01 = fmaf(wx1, xt, b01);
            float z10 = b10, z11 = b11, z20 = b20, z21 = b21;
#pragma unroll
            for (int k = 0; k < 6; ++k) {
                z00 = fmaf(whh0a[k], h0a[k], z00);
                z01 = fmaf(whh0b[k], h0a[k], z01);
            }
#pragma unroll
            for (int k = 0; k < 6; ++k) {
                z10 = fmaf(whh1a[k], h1a[k], z10);
                z11 = fmaf(whh1b[k], h1a[k], z11);
            }
#pragma unroll
            for (int k = 0; k < 6; ++k) {
                z20 = fmaf(whh2a[k], h2a[k], z20);
                z21 = fmaf(whh2b[k], h2a[k], z21);
            }

            // ---------------- layer 0 ----------------
            {
                float a0 = act(z00, A0, B0);      // p0: i   p1: g
                float a1 = act(z01, 1.0f, 0.0f);  // p0: f   p1: o
                float gx = swz<XCHG>(a0);
                float ox = swz<XCHG>(a1);
                c0 = fmaf(a1, c0, a0 * gx);       // valid on p0 lanes
                float h = ox * tanh_c(c0);
                BCAST6(h0a, h);                   // reads p0 lanes 0..5
            }

            // ---------------- layer 1 ----------------
#pragma unroll
            for (int k = 0; k < 6; ++k) {
                z10 = fmaf(wih1a[k], h0a[k], z10);
                z11 = fmaf(wih1b[k], h0a[k], z11);
            }
            {
                float a0 = act(z10, A0, B0);
                float a1 = act(z11, 1.0f, 0.0f);
                float gx = swz<XCHG>(a0);
                float ox = swz<XCHG>(a1);
                c1 = fmaf(a1, c1, a0 * gx);
                float h = ox * tanh_c(c1);
                BCAST6(h1a, h);
            }

            // ---------------- layer 2 ----------------
#pragma unroll
            for (int k = 0; k < 6; ++k) {
                z20 = fmaf(wih2a[k], h1a[k], z20);
                z21 = fmaf(wih2b[k], h1a[k], z21);
            }
            {
                float a0 = act(z20, A0, B0);
                float a1 = act(z21, 1.0f, 0.0f);
                float gx = swz<XCHG>(a0);
                float ox = swz<XCHG>(a1);
                c2 = fmaf(a1, c2, a0 * gx);
                float h = ox * tanh_c(c2);
                BCAST6(h2a, h);
            }
        }
        q = qn;
    }

    // ---- final FC ----
    if (sub == 0) {
        float o = fcb[0];
#pragma unroll
        for (int k = 0; k < 6; ++k)
            o = fmaf(fcw[k], h2a[k], o);
        out[b] = o;
    }
}

extern "C" void kernel_launch(void* const* d_in, const int* in_sizes, int n_in,
                              void* d_out, int out_size, void* d_ws, size_t ws_size,
                              hipStream_t stream) {
    const float* x    = (const float*)d_in[0];
    const float* Wih0 = (const float*)d_in[1];
    const float* Whh0 = (const float*)d_in[2];
    const float* bih0 = (const float*)d_in[3];
    const float* bhh0 = (const float*)d_in[4];
    const float* Wih1 = (const float*)d_in[5];
    const float* Whh1 = (const float*)d_in[6];
    const float* bih1 = (const float*)d_in[7];
    const float* bhh1 = (const float*)d_in[8];
    const float* Wih2 = (const float*)d_in[9];
    const float* Whh2 = (const float*)d_in[10];
    const float* bih2 = (const float*)d_in[11];
    const float* bhh2 = (const float*)d_in[12];
    const float* fcw  = (const float*)d_in[13];
    const float* fcb  = (const float*)d_in[14];
    float* out = (float*)d_out;

    const int B = out_size;            // 8192
    const int threads = B * 16;        // 16 lanes per batch element
    const int block = 256;
    const int grid = threads / block;  // 512 blocks -> 2 waves/SIMD
    lstm3_kernel<<<grid, block, 0, stream>>>(
        x, Wih0, Whh0, bih0, bhh0, Wih1, Whh1, bih1, bhh1,
        Wih2, Whh2, bih2, bhh2, fcw, fcb, out);
}